// Round 12
// baseline (98.678 us; speedup 1.0000x reference)
//
#include <hip/hip_runtime.h>
#include <hip/hip_bf16.h>
#include <math.h>

// Problem constants
#define NB 2
#define NS 2048
#define ND 1024
#define NH 16
#define HD 64
#define BS (NB*NS)     // 4096 tokens
#define D3 (3*ND)      // 3072
#define NT (NS/64)     // 32 q-tiles of 64

typedef __bf16 bf16;
typedef __bf16 bf16x4 __attribute__((ext_vector_type(4)));
typedef __bf16 bf16x8 __attribute__((ext_vector_type(8)));
typedef float f32x4 __attribute__((ext_vector_type(4)));

#define MFMA16(a,b,c) __builtin_amdgcn_mfma_f32_16x16x32_bf16(a,b,c,0,0,0)

static __device__ inline f32x4 zero4() { f32x4 z; z[0]=0.f; z[1]=0.f; z[2]=0.f; z[3]=0.f; return z; }

// global -> LDS direct copy, 16B per lane; lds base must be wave-uniform.
__device__ __forceinline__ void gload_lds16(const bf16* g, bf16* l) {
    __builtin_amdgcn_global_load_lds(
        (__attribute__((address_space(1))) unsigned int*)g,
        (__attribute__((address_space(3))) unsigned int*)l, 16, 0, 0);
}

// ---------------- prep: f32->bf16 for x/w_in/w_out + RoPE float2 table, one launch ----------------
#define CVT1 (BS*ND/8)          // 524288
#define CVT2 (D3*ND/8)          // 393216
#define CVT3 (ND*ND/8)          // 131072
#define CVTN (CVT1+CVT2+CVT3)   // 1048576
__global__ __launch_bounds__(256) void prep(
    const float* __restrict__ x, const float* __restrict__ w_in, const float* __restrict__ w_out,
    bf16* __restrict__ xb, bf16* __restrict__ winb, bf16* __restrict__ woutb,
    float2* __restrict__ csT)
{
    int i = blockIdx.x * 256 + threadIdx.x;
    if (i < CVTN) {
        const float* in; bf16* out; int j;
        if (i < CVT1)            { in = x;     out = xb;    j = i; }
        else if (i < CVT1+CVT2)  { in = w_in;  out = winb;  j = i - CVT1; }
        else                     { in = w_out; out = woutb; j = i - CVT1 - CVT2; }
        const float4* p = (const float4*)in;
        float4 a = p[j*2], b = p[j*2+1];
        bf16x8 o;
        o[0]=(bf16)a.x; o[1]=(bf16)a.y; o[2]=(bf16)a.z; o[3]=(bf16)a.w;
        o[4]=(bf16)b.x; o[5]=(bf16)b.y; o[6]=(bf16)b.z; o[7]=(bf16)b.w;
        ((bf16x8*)out)[j] = o;
    } else {
        int k = i - CVTN;                      // [0, NS*32)
        int s = k >> 5, j = k & 31;
        float inv = __expf(-(float)j * (9.210340372f * 0.03125f));  // 10000^(-j/32)
        float ang = (float)s * inv;
        csT[k] = make_float2(cosf(ang), sinf(ang));
    }
}

// ---------------- GEMM: C[m,n] = sum_k A[m,k]*B[n,k], bf16, BK=64, swizzled LDS ----------------
// Double-buffered LDS + counted vmcnt (never drains to 0 in the main loop).
// EPI==0: f32 store. EPI==1: fused RoPE -> Q/K head-major [bh][s][d]; V^T k-permuted [bh][d][s'].
template<int EPI>
__global__ __launch_bounds__(256) void gemm_bt(
    const bf16* __restrict__ A, const bf16* __restrict__ Bm,
    float* __restrict__ C, bf16* __restrict__ Qb, bf16* __restrict__ Kb, bf16* __restrict__ Vt,
    const float2* __restrict__ csT,
    int M, int N, int K)
{
    __shared__ bf16 As[2][128*64];
    __shared__ bf16 Bs[2][128*64];
    int t = threadIdx.x;
    int lane = t & 63, w = t >> 6;
    int wr = w >> 1, wc = w & 1;
    int lr = lane & 15, lg = lane >> 4;
    int m0 = blockIdx.y * 128, n0 = blockIdx.x * 128;

    int srow = lane >> 3;                 // 0..7
    int schunk = (lane & 7) ^ srow;       // XOR-swizzled source chunk
    const bf16* gA = &A [(size_t)(m0 + w*32 + srow)*K + schunk*8];
    const bf16* gB = &Bm[(size_t)(n0 + w*32 + srow)*K + schunk*8];

    auto stage = [&](int kt) {
        int buf = kt & 1;
        bf16* lA = &As[buf][w*2048];
        bf16* lB = &Bs[buf][w*2048];
        int k0 = kt * 64;
        #pragma unroll
        for (int i=0;i<4;i++) {
            gload_lds16(gA + (size_t)(i*8)*K + k0, lA + i*512);
            gload_lds16(gB + (size_t)(i*8)*K + k0, lB + i*512);
        }
    };

    f32x4 acc[4][4];
    for (int m=0;m<4;m++) for (int n=0;n<4;n++) acc[m][n] = zero4();

    int nt = K >> 6;
    stage(0);
    stage(1);

    for (int kt = 0; kt < nt; kt++) {
        int cur = kt & 1;
        if (kt < nt-1) asm volatile("s_waitcnt vmcnt(8)" ::: "memory");
        else           asm volatile("s_waitcnt vmcnt(0)" ::: "memory");
        __builtin_amdgcn_s_barrier();
        __builtin_amdgcn_sched_barrier(0);

        bf16x8 af[2][4], bfr[2][4];
        #pragma unroll
        for (int ks=0;ks<2;ks++) {
            #pragma unroll
            for (int m=0;m<4;m++) {
                int row = wr*64 + m*16 + lr;
                af[ks][m] = *(const bf16x8*)&As[cur][row*64 + (((ks*4+lg) ^ (row&7))*8)];
            }
            #pragma unroll
            for (int n=0;n<4;n++) {
                int row = wc*64 + n*16 + lr;
                bfr[ks][n] = *(const bf16x8*)&Bs[cur][row*64 + (((ks*4+lg) ^ (row&7))*8)];
            }
        }
        asm volatile("s_waitcnt lgkmcnt(0)" ::: "memory");
        __builtin_amdgcn_sched_barrier(0);
        __builtin_amdgcn_s_barrier();
        __builtin_amdgcn_sched_barrier(0);

        if (kt + 2 < nt) stage(kt + 2);

        __builtin_amdgcn_s_setprio(1);
        #pragma unroll
        for (int ks=0;ks<2;ks++)
            #pragma unroll
            for (int m=0;m<4;m++)
                #pragma unroll
                for (int n=0;n<4;n++)
                    acc[m][n] = MFMA16(af[ks][m], bfr[ks][n], acc[m][n]);
        __builtin_amdgcn_s_setprio(0);
    }

    if (EPI == 0) {
        for (int m=0;m<4;m++) for (int n=0;n<4;n++) {
            int grow = m0 + wr*64 + m*16 + lg*4;
            int gcol = n0 + wc*64 + n*16 + lr;
            for (int r=0;r<4;r++)
                C[(size_t)(grow+r) * N + gcol] = acc[m][n][r];
        }
    } else {
        int which = n0 >> 10;
        if (which == 2) {
            for (int m=0;m<4;m++) for (int n=0;n<4;n++) {
                int grow = m0 + wr*64 + m*16 + lg*4;
                int gcol = n0 + wc*64 + n*16 + lr;
                int h = (gcol & 1023) >> 6, d = gcol & 63;
                int b = grow >> 11, s0 = grow & (NS-1);
                int shi = s0 & ~63, j = s0 & 63;
                int kp = ((j>>5)&1)*32 + ((j>>2)&3)*8 + ((j>>4)&1)*4;
                bf16x4 pv;
                for (int r=0;r<4;r++) pv[r] = (bf16)acc[m][n][r];
                *(bf16x4*)&Vt[((size_t)((b*NH + h)*HD + d))*NS + shi + kp] = pv;
            }
        } else {
            const float qs = 0.125f * 1.44269504f;
            bf16* dst = (which == 0) ? Qb : Kb;
            for (int m=0;m<4;m++) {
                int grow = m0 + wr*64 + m*16 + lg*4;
                #pragma unroll
                for (int n=0;n<2;n++) {
                    int gcol = n0 + wc*64 + n*16 + lr;
                    int h = (gcol & 1023) >> 6, j = gcol & 63;
                    #pragma unroll
                    for (int r=0;r<4;r++) {
                        int gm = grow + r;
                        int b = gm >> 11, s = gm & (NS-1);
                        float2 cs = csT[(s<<5)+j];
                        float x1 = acc[m][n][r], x2 = acc[m][n+2][r];
                        float y1 = x1*cs.x - x2*cs.y;
                        float y2 = x2*cs.x + x1*cs.y;
                        if (which == 0) { y1 *= qs; y2 *= qs; }
                        size_t off = ((size_t)((b*NH + h)*NS + s))*HD;
                        dst[off + j]      = (bf16)y1;
                        dst[off + j + 32] = (bf16)y2;
                    }
                }
            }
        }
    }
}

// ---------------- causal flash attention: uniform pair blocks, max-free softmax ----------------
// 512 blocks; block = (bh = wgid&31, qa = wgid>>5 in [0,16)), handles q-tiles {qa, 31-qa}.
// Every block processes exactly 33 tile-units -> zero drain at 2 blocks/CU.
// K/V fragments hoisted once per kv-tile, shared by both q-tiles (2x MFMA per LDS read).
__global__ __launch_bounds__(256, 2) void attn_fwd(
    const bf16* __restrict__ Qb, const bf16* __restrict__ Kb, const bf16* __restrict__ Vp,
    bf16* __restrict__ AO)
{
    __shared__ bf16 Ks[2][64*64];      // [buf][key][d], chunk-swizzled
    __shared__ bf16 Vs[2][64*64];      // [buf][d][k'],  chunk-swizzled
    int t = threadIdx.x;
    int lane = t & 63, w = t >> 6;
    int lr = lane & 15, lg = lane >> 4;
    int wgid = blockIdx.x;
    int bh = wgid & 31;
    int qa = wgid >> 5;                // 0..15
    int qb = (NT-1) - qa;              // 31..16
    int b = bh >> 4, h = bh & 15;
    size_t base = (size_t)bh * NS * HD;
    int q0a = qa*64 + w*16, q0b = qb*64 + w*16;

    bf16x8 qfA[2], qfB[2];
    #pragma unroll
    for (int c=0;c<2;c++) {
        qfA[c] = *(const bf16x8*)&Qb[base + (size_t)(q0a+lr)*HD + c*32 + lg*8];
        qfB[c] = *(const bf16x8*)&Qb[base + (size_t)(q0b+lr)*HD + c*32 + lg*8];
    }

    bf16x8 onesf;
    #pragma unroll
    for (int i=0;i<8;i++) onesf[i] = (bf16)1.0f;

    f32x4 oA[4], oB[4];
    f32x4 laccA = zero4(), laccB = zero4();
    #pragma unroll
    for (int n=0;n<4;n++) { oA[n]=zero4(); oB[n]=zero4(); }
    f32x4 minit;                        // C-init = -12: constant softmax shift for free
    minit[0] = -12.f; minit[1] = -12.f; minit[2] = -12.f; minit[3] = -12.f;

    // staging addressing (reg-staged for swizzled writes)
    int srow = t >> 3;                 // 0..31
    int sch  = t & 7;
    int sslot = sch ^ (srow & 7);
    bf16x8 kr[2], vr[2];

    auto load_window = [&](int kv0) {
        #pragma unroll
        for (int i=0;i<2;i++)
            kr[i] = *(const bf16x8*)&Kb[base + (size_t)(kv0 + i*32 + srow)*HD + sch*8];
        #pragma unroll
        for (int i=0;i<2;i++)
            vr[i] = *(const bf16x8*)&Vp[base + (size_t)(i*32 + srow)*NS + kv0 + sch*8];
    };
    auto store_window = [&](int buf) {
        #pragma unroll
        for (int i=0;i<2;i++)
            *(bf16x8*)&Ks[buf][(i*32 + srow)*64 + sslot*8] = kr[i];
        #pragma unroll
        for (int i=0;i<2;i++)
            *(bf16x8*)&Vs[buf][(i*32 + srow)*64 + sslot*8] = vr[i];
    };

    // process one q-tile against the hoisted K/V fragments (max-free softmax)
    auto process = [&](bf16x8 (&kf)[4][2], bf16x8 (&vf)[2][4], bf16x8* qf,
                       f32x4& lacc, f32x4* o, bool diag, int kv0, int q0) {
        f32x4 sc[4];
        __builtin_amdgcn_s_setprio(1);
        #pragma unroll
        for (int kb=0;kb<4;kb++) {
            sc[kb] = MFMA16(kf[kb][0], qf[0], minit);
            sc[kb] = MFMA16(kf[kb][1], qf[1], sc[kb]);
        }
        __builtin_amdgcn_s_setprio(0);
        if (diag) {
            int qi = q0 + lr;
            #pragma unroll
            for (int kb=0;kb<4;kb++)
                #pragma unroll
                for (int rr=0;rr<4;rr++)
                    if (kv0 + kb*16 + lg*4 + rr > qi) sc[kb][rr] = -__builtin_inff();
        }
        bf16x8 pa[2];
        #pragma unroll
        for (int c=0;c<2;c++) {
            bf16x8 v;
            #pragma unroll
            for (int i=0;i<8;i++) v[i] = (bf16)exp2f(sc[c*2 + (i>>2)][i&3]);
            pa[c] = v;
        }
        __builtin_amdgcn_s_setprio(1);
        #pragma unroll
        for (int c=0;c<2;c++) {
            lacc = MFMA16(onesf, pa[c], lacc);
            #pragma unroll
            for (int n=0;n<4;n++)
                o[n] = MFMA16(vf[c][n], pa[c], o[n]);
        }
        __builtin_amdgcn_s_setprio(0);
    };

    for (int kt = 0; kt <= qb; kt++) {
        if (kt == 0) { load_window(0); store_window(0); __syncthreads(); }
        int cur = kt & 1;
        int kv0 = kt*64;
        bool last = (kt == qb);
        if (!last) load_window(kv0 + 64);          // issue next-tile loads early (T14)

        const bf16* ksb = &Ks[cur][0];
        const bf16* vsb = &Vs[cur][0];

        // hoist K/V fragments once; both q-tiles reuse them (halves LDS reads per unit work)
        bf16x8 kf[4][2], vf[2][4];
        #pragma unroll
        for (int kb=0;kb<4;kb++) {
            int row = kb*16 + lr;
            kf[kb][0] = *(const bf16x8*)&ksb[row*64 + ((lg     ^ (row&7))*8)];
            kf[kb][1] = *(const bf16x8*)&ksb[row*64 + (((4+lg) ^ (row&7))*8)];
        }
        #pragma unroll
        for (int c=0;c<2;c++)
            #pragma unroll
            for (int n=0;n<4;n++) {
                int row = n*16 + lr;
                vf[c][n] = *(const bf16x8*)&vsb[row*64 + (((c*4+lg) ^ (row&7))*8)];
            }

        process(kf, vf, qfB, laccB, oB, last, kv0, q0b);
        if (kt <= qa)
            process(kf, vf, qfA, laccA, oA, kt==qa, kv0, q0a);

        if (!last) { store_window(cur^1); __syncthreads(); }
    }

    // epilogue: normalize, write [b,s,h,d] as bf16x4 chunks (lane owns q-row lr, d-slice lg*4)
    float invB = 1.0f / laccB[0];
    float invA = 1.0f / laccA[0];
    int qB = q0b + lr, qA = q0a + lr;
    #pragma unroll
    for (int n=0;n<4;n++) {
        bf16x4 o1, o2;
        #pragma unroll
        for (int rr=0;rr<4;rr++) {
            o1[rr] = (bf16)(oB[n][rr] * invB);
            o2[rr] = (bf16)(oA[n][rr] * invA);
        }
        *(bf16x4*)&AO[((size_t)(b*NS + qB)*NH + h)*HD + n*16 + lg*4] = o1;
        *(bf16x4*)&AO[((size_t)(b*NS + qA)*NH + h)*HD + n*16 + lg*4] = o2;
    }
}

extern "C" void kernel_launch(void* const* d_in, const int* in_sizes, int n_in,
                              void* d_out, int out_size, void* d_ws, size_t ws_size,
                              hipStream_t stream) {
    const float* x     = (const float*)d_in[0];
    const float* w_in  = (const float*)d_in[1];
    const float* w_out = (const float*)d_in[2];
    float* out = (float*)d_out;

    char* p = (char*)d_ws;
    bf16* xb    = (bf16*)p; p += (size_t)BS*ND*2;          // 8 MB
    bf16* winb  = (bf16*)p; p += (size_t)D3*ND*2;          // 6 MB
    bf16* woutb = (bf16*)p; p += (size_t)ND*ND*2;          // 2 MB
    bf16* Qb    = (bf16*)p; p += (size_t)NB*NH*NS*HD*2;    // 8 MB
    bf16* Kb    = (bf16*)p; p += (size_t)NB*NH*NS*HD*2;    // 8 MB
    bf16* Vp    = (bf16*)p; p += (size_t)NB*NH*NS*HD*2;    // 8 MB  (V^T, k-permuted, [bh][d][s'])
    bf16* AO    = (bf16*)p; p += (size_t)BS*ND*2;          // 8 MB
    float2* csT = (float2*)p; p += (size_t)NS*32*8;        // 512 KB cos/sin interleaved

    prep<<<(CVTN + NS*32)/256, 256, 0, stream>>>(x, w_in, w_out, xb, winb, woutb, csT);
    gemm_bt<1><<<dim3(D3/128, BS/128), 256, 0, stream>>>(xb, winb, nullptr, Qb, Kb, Vp,
                                                         csT, BS, D3, ND);
    attn_fwd<<<NB*NH*(NT/2), 256, 0, stream>>>(Qb, Kb, Vp, AO);
    gemm_bt<0><<<dim3(ND/128, BS/128), 256, 0, stream>>>(AO, woutb, out, nullptr, nullptr, nullptr,
                                                         nullptr, BS, ND, ND);
}